// Round 1
// baseline (113.282 us; speedup 1.0000x reference)
//
#include <hip/hip_runtime.h>

#define BB 64
#define TT 256
#define HH 200
#define KK 48
#define KQ 12          // k's per wave (4 waves cover 48)
#define C4 50          // HH/4 float4 chunks per row
#define FSTRIDE4 51    // padded row stride in float4 units (odd -> conflict-free)

__global__ __launch_bounds__(256, 2)
void crf_fused_kernel(const float* __restrict__ feats,
                      const float* __restrict__ W_e,
                      const float* __restrict__ b_e,
                      const int*   __restrict__ targets,
                      const int*   __restrict__ mask,
                      const int*   __restrict__ start_tag_p,  // unused by math
                      const int*   __restrict__ end_tag_p,
                      float*       __restrict__ out)
{
    __shared__ float4 f_lds[64 * FSTRIDE4];   // 52224 B feats tile
    __shared__ float  m_arr[4 * 64];
    __shared__ float  s_arr[4 * 64];
    __shared__ float  g_arr[4 * 64];
    __shared__ float  e_arr[4 * 64];
    __shared__ int    len_sh;

    const int tid  = threadIdx.x;
    const int lane = tid & 63;
    const int w    = __builtin_amdgcn_readfirstlane(tid >> 6);  // wave id, force SGPR
    const int bidx = blockIdx.x >> 2;   // batch b
    const int tq   = blockIdx.x & 3;    // t-tile (64 t's each)

    if (tid == 0) len_sh = 0;

    // ---- stage feats tile: rows [tq*64, tq*64+64) of batch b, coalesced ----
    const float4* feats4 = reinterpret_cast<const float4*>(feats) +
                           (size_t)(bidx * TT + tq * 64) * C4;
    for (int i = tid; i < 64 * C4; i += 256) {
        int r = i / C4;
        int c = i - r * C4;
        f_lds[r * FSTRIDE4 + c] = feats4[i];
    }

    // ---- block-wide mask length (tid covers all 256 t's of this b) ----
    {
        int mv = mask[bidx * TT + tid];
        #pragma unroll
        for (int off = 32; off >= 1; off >>= 1) mv += __shfl_xor(mv, off);
        if (lane == 0) atomicAdd(&len_sh, mv);
    }
    __syncthreads();

    // ---- emission dot products: lane -> t, wave -> k-quarter ----
    const int t_glob = tq * 64 + lane;
    const int kbase  = w * KQ;   // SGPR
    const float4* W4 = reinterpret_cast<const float4*>(W_e);

    float acc[KQ];
    #pragma unroll
    for (int kk = 0; kk < KQ; ++kk) acc[kk] = b_e[kbase + kk];  // uniform -> s_load

    const float4* frow = &f_lds[lane * FSTRIDE4];
    for (int c4 = 0; c4 < C4; ++c4) {
        const float4 f = frow[c4];
        #pragma unroll
        for (int kk = 0; kk < KQ; ++kk) {
            const float4 wv = W4[(kbase + kk) * C4 + c4];  // uniform -> s_load_dwordx4
            acc[kk] = fmaf(f.x, wv.x,
                      fmaf(f.y, wv.y,
                      fmaf(f.z, wv.z,
                      fmaf(f.w, wv.w, acc[kk]))));
        }
    }

    // ---- per-lane partials over this wave's 12 k's ----
    const int ET = end_tag_p[0];
    const int tg = targets[bidx * TT + t_glob];
    const int kg = tg % KK;   // targets % K (values >= 0)

    float m = acc[0];
    #pragma unroll
    for (int kk = 1; kk < KQ; ++kk) m = fmaxf(m, acc[kk]);
    float s = 0.0f, gp = 0.0f, ep = 0.0f;
    #pragma unroll
    for (int kk = 0; kk < KQ; ++kk) {
        s += expf(acc[kk] - m);
        const int kglob = kbase + kk;
        gp += (kglob == kg) ? acc[kk] : 0.0f;
        ep += (kglob == ET) ? acc[kk] : 0.0f;
    }
    m_arr[w * 64 + lane] = m;
    s_arr[w * 64 + lane] = s;
    g_arr[w * 64 + lane] = gp;
    e_arr[w * 64 + lane] = ep;
    __syncthreads();

    // ---- wave 0 combines quarters, forms per-t contribution, reduces ----
    if (tid < 64) {
        const int l = tid;
        const float m0 = m_arr[0 * 64 + l], m1 = m_arr[1 * 64 + l];
        const float m2 = m_arr[2 * 64 + l], m3 = m_arr[3 * 64 + l];
        const float M  = fmaxf(fmaxf(m0, m1), fmaxf(m2, m3));
        const float S  = s_arr[0 * 64 + l] * expf(m0 - M)
                       + s_arr[1 * 64 + l] * expf(m1 - M)
                       + s_arr[2 * 64 + l] * expf(m2 - M)
                       + s_arr[3 * 64 + l] * expf(m3 - M);
        const float lse  = M + logf(S);
        const float gold = g_arr[0 * 64 + l] + g_arr[1 * 64 + l]
                         + g_arr[2 * 64 + l] + g_arr[3 * 64 + l];
        const float eend = e_arr[0 * 64 + l] + e_arr[1 * 64 + l]
                         + e_arr[2 * 64 + l] + e_arr[3 * 64 + l];
        const int len = len_sh;
        const int gt  = tq * 64 + l;

        float c = 0.0f;
        if (gt < len)      c -= gold;        // gold score (negated)
        if (gt == len - 1) c += eend;        // last step: emission[end_tag]
        else if (gt < len - 1) c += lse;     // forward LSE accumulation

        #pragma unroll
        for (int off = 32; off >= 1; off >>= 1) c += __shfl_xor(c, off);
        if (l == 0) atomicAdd(out + bidx, c);
    }
}

extern "C" void kernel_launch(void* const* d_in, const int* in_sizes, int n_in,
                              void* d_out, int out_size, void* d_ws, size_t ws_size,
                              hipStream_t stream) {
    const float* feats   = (const float*)d_in[0];
    const float* W_e     = (const float*)d_in[1];
    const float* b_e     = (const float*)d_in[2];
    const int*   targets = (const int*)d_in[3];
    const int*   mask    = (const int*)d_in[4];
    const int*   st      = (const int*)d_in[5];
    const int*   et      = (const int*)d_in[6];
    float*       out     = (float*)d_out;

    hipMemsetAsync(out, 0, BB * sizeof(float), stream);  // atomic accumulators
    crf_fused_kernel<<<dim3(BB * 4), dim3(256), 0, stream>>>(
        feats, W_e, b_e, targets, mask, st, et, out);
}

// Round 2
// 94.304 us; speedup vs baseline: 1.2012x; 1.2012x over previous
//
#include <hip/hip_runtime.h>

#define BB 64
#define TT 256
#define HH 200
#define KK 48
#define C4 50        // HH/4 float4 per row
#define TPB 16       // t rows per block tile
#define FS4 51       // LDS row stride in float4 (odd -> conflict-free b128)

__global__ __launch_bounds__(256, 4)
void crf_fused_kernel(const float* __restrict__ feats,
                      const float* __restrict__ W_e,
                      const float* __restrict__ b_e,
                      const int*   __restrict__ targets,
                      const int*   __restrict__ mask,
                      const int*   __restrict__ end_tag_p,
                      float*       __restrict__ out)
{
    __shared__ float4 f_lds[TPB * FS4];                 // 13056 B
    __shared__ float  m_arr[4][TPB], s_arr[4][TPB];
    __shared__ float  g_arr[4][TPB], e_arr[4][TPB];

    const int tid  = threadIdx.x;
    const int lane = tid & 63;
    const int w    = tid >> 6;          // wave id 0..3 -> k-dozen
    const int bidx = blockIdx.x >> 4;   // batch
    const int tq   = blockIdx.x & 15;   // t-tile of 16

    // ---- stage feats tile (16 rows x 50 float4), coalesced ----
    const float4* feats4 = reinterpret_cast<const float4*>(feats) +
                           (size_t)(bidx * TT + tq * TPB) * C4;
    for (int i = tid; i < TPB * C4; i += 256) {
        const int r = i / C4, c = i - r * C4;
        f_lds[r * FS4 + c] = feats4[i];
    }

    // ---- wave-redundant mask length (one int4 per lane covers all 256 t) ----
    int len;
    {
        const int4 mv4 = reinterpret_cast<const int4*>(mask + bidx * TT)[lane];
        int mv = mv4.x + mv4.y + mv4.z + mv4.w;
        #pragma unroll
        for (int off = 32; off >= 1; off >>= 1) mv += __shfl_xor(mv, off);
        len = mv;
    }
    __syncthreads();

    // ---- lane mapping: t_loc = lane&15, k-group = lane>>4; 3 k's per lane ----
    const int t_loc  = lane & 15;
    const int kg     = lane >> 4;            // 0..3
    const int k0     = w * 12 + kg * 3;      // lane owns k0..k0+2
    const int t_glob = tq * TPB + t_loc;

    const float4* W4   = reinterpret_cast<const float4*>(W_e);
    const float4* wp0  = W4 + (size_t)(k0 + 0) * C4;
    const float4* wp1  = W4 + (size_t)(k0 + 1) * C4;
    const float4* wp2  = W4 + (size_t)(k0 + 2) * C4;
    const float4* frow = &f_lds[t_loc * FS4];

    float a0 = b_e[k0], a1 = b_e[k0 + 1], a2 = b_e[k0 + 2];
    #pragma unroll 2
    for (int c = 0; c < C4; ++c) {
        const float4 f  = frow[c];
        const float4 w0 = wp0[c];
        const float4 w1 = wp1[c];
        const float4 w2 = wp2[c];
        a0 = fmaf(f.x,w0.x, fmaf(f.y,w0.y, fmaf(f.z,w0.z, fmaf(f.w,w0.w, a0))));
        a1 = fmaf(f.x,w1.x, fmaf(f.y,w1.y, fmaf(f.z,w1.z, fmaf(f.w,w1.w, a1))));
        a2 = fmaf(f.x,w2.x, fmaf(f.y,w2.y, fmaf(f.z,w2.z, fmaf(f.w,w2.w, a2))));
    }

    // ---- per-lane partials over its 3 k's ----
    const int ET  = end_tag_p[0];
    const int tgt = targets[bidx * TT + t_glob] % KK;

    float m = fmaxf(fmaxf(a0, a1), a2);
    float s = expf(a0 - m) + expf(a1 - m) + expf(a2 - m);
    float g = ((k0     == tgt) ? a0 : 0.0f)
            + ((k0 + 1 == tgt) ? a1 : 0.0f)
            + ((k0 + 2 == tgt) ? a2 : 0.0f);
    float e = ((k0     == ET) ? a0 : 0.0f)
            + ((k0 + 1 == ET) ? a1 : 0.0f)
            + ((k0 + 2 == ET) ? a2 : 0.0f);

    // ---- merge the 4 k-groups in-register (lanes xor 16, 32) ----
    #pragma unroll
    for (int off = 16; off <= 32; off <<= 1) {
        const float om = __shfl_xor(m, off);
        const float os = __shfl_xor(s, off);
        const float nm = fmaxf(m, om);
        s = s * expf(m - nm) + os * expf(om - nm);
        m = nm;
        g += __shfl_xor(g, off);
        e += __shfl_xor(e, off);
    }
    if (lane < TPB) {
        m_arr[w][t_loc] = m; s_arr[w][t_loc] = s;
        g_arr[w][t_loc] = g; e_arr[w][t_loc] = e;
    }
    __syncthreads();

    // ---- final: combine 4 waves per t, form contribution, reduce 16 t ----
    if (tid < TPB) {
        const int t = tid;
        float M = m_arr[0][t], S = s_arr[0][t];
        #pragma unroll
        for (int i2 = 1; i2 < 4; ++i2) {
            const float om = m_arr[i2][t], os = s_arr[i2][t];
            const float nm = fmaxf(M, om);
            S = S * expf(M - nm) + os * expf(om - nm);
            M = nm;
        }
        const float lse  = M + logf(S);
        const float gold = g_arr[0][t] + g_arr[1][t] + g_arr[2][t] + g_arr[3][t];
        const float eend = e_arr[0][t] + e_arr[1][t] + e_arr[2][t] + e_arr[3][t];
        const int gt = tq * TPB + t;

        float c = 0.0f;
        if (gt < len)          c -= gold;
        if (gt == len - 1)     c += eend;
        else if (gt < len - 1) c += lse;

        #pragma unroll
        for (int off = 8; off >= 1; off >>= 1) c += __shfl_xor(c, off);
        if (t == 0) atomicAdd(out + bidx, c);
    }
}

extern "C" void kernel_launch(void* const* d_in, const int* in_sizes, int n_in,
                              void* d_out, int out_size, void* d_ws, size_t ws_size,
                              hipStream_t stream) {
    const float* feats   = (const float*)d_in[0];
    const float* W_e     = (const float*)d_in[1];
    const float* b_e     = (const float*)d_in[2];
    const int*   targets = (const int*)d_in[3];
    const int*   mask    = (const int*)d_in[4];
    const int*   et      = (const int*)d_in[6];
    float*       out     = (float*)d_out;

    hipMemsetAsync(out, 0, BB * sizeof(float), stream);
    crf_fused_kernel<<<dim3(BB * (TT / TPB)), dim3(256), 0, stream>>>(
        feats, W_e, b_e, targets, mask, et, out);
}